// Round 11
// baseline (375.024 us; speedup 1.0000x reference)
//
#include <hip/hip_runtime.h>
#include <math.h>
#include <utility>

// ---------------------------------------------------------------------------
// FCTP(64x0e+32x1o+16x2e -> 64x0e) + 3-layer SiLU MLP, fwd + input-grad.
//   fwd+mlp FUSED (r11): fwd's 4-wave reduce epilogue writes h directly into
//        the mlp's sact[64][65] LDS tile (wave wv holds column stripe
//        16wv+l15 = mlp's ch-group) — kills the 25MB h round-trip + a launch.
//        fwd body = r9 SPLIT=1 (r10's 4-way split regressed: replicated
//        prologue/epilogue, FETCH 25->49MB, WRITE 12.5->50MB).
//   bwd_l0 : 4-wave WGs, register-consume, padded x0 tile, wb prefetch (r9).
//   bwd_l12: independent-wave private-dPb LDS transpose.
// ---------------------------------------------------------------------------

typedef short bf8 __attribute__((ext_vector_type(8)));
typedef float f4 __attribute__((ext_vector_type(4)));

constexpr int IRR = 240;

// padded fwd pair enumeration: l0: [0,2112) real 2080 ; l1: [2112,2688) real 528
// l2: [2688,2880) real 136.  45 chunks of 64.
constexpr int NP = 2880;

struct PTab { short u[NP]; short v[NP]; signed char l[NP]; };
constexpr PTab build_ptab() {
    PTab t{}; int p = 0;
    for (int u = 0; u < 64; u++) for (int v = u; v < 64; v++) { t.u[p]=(short)u; t.v[p]=(short)v; t.l[p]=0; p++; }
    while (p < 2112) { t.l[p] = -1; p++; }
    for (int u = 0; u < 32; u++) for (int v = u; v < 32; v++) { t.u[p]=(short)u; t.v[p]=(short)v; t.l[p]=1; p++; }
    while (p < 2688) { t.l[p] = -1; p++; }
    for (int u = 0; u < 16; u++) for (int v = u; v < 16; v++) { t.u[p]=(short)u; t.v[p]=(short)v; t.l[p]=2; p++; }
    while (p < NP)   { t.l[p] = -1; p++; }
    return t;
}
constexpr PTab PT = build_ptab();

// ws layout (bytes)
constexpr size_t B_WTF = 0;                       // bf16 [64 chan][2880 pair]
constexpr size_t B_WB  = (size_t)64 * NP * 2;     // 368640 : bf16 [5376 pair][64 chan]
constexpr size_t B_A1T = B_WB + (size_t)5376 * 64 * 2;   // 1056768
constexpr size_t B_A2T = B_A1T + 16384;
constexpr size_t B_A3T = B_A2T + 16384;
constexpr size_t B_DG2 = B_A3T + 16384;
constexpr size_t B_H   = B_DG2 + 256;             // dh only (h never hits global)

__device__ __forceinline__ unsigned short f2bf(float x) {
    unsigned int u = __float_as_uint(x);
    return (unsigned short)((u + 0x7fffu + ((u >> 16) & 1u)) >> 16);
}
__device__ __forceinline__ unsigned pack2(float a, float b) {   // -> [bf16(a), bf16(b)]
    unsigned ua = __float_as_uint(a) + 0x8000u;   // round-half-up (0.5 ulp)
    unsigned ub = __float_as_uint(b) + 0x8000u;
    return __builtin_amdgcn_perm(ub, ua, 0x07060302u);
}

// ---------------------------------------------------------------------------
__global__ void prep_kernel(const float* __restrict__ W0, const float* __restrict__ W1,
                            const float* __restrict__ W2, const float* __restrict__ A1,
                            const float* __restrict__ A2, const float* __restrict__ A3,
                            unsigned short* __restrict__ wtf, unsigned short* __restrict__ wb,
                            float* __restrict__ a1t, float* __restrict__ a2t,
                            float* __restrict__ a3t, float* __restrict__ dg2)
{
    int idx = blockIdx.x * blockDim.x + threadIdx.x;
    const double c0 = 1.0 / sqrt(5376.0);
    const double cl_[3] = { c0, c0 / sqrt(3.0), c0 / sqrt(5.0) };
    // A) wtf[chan][2880] (padded fwd table, zero pads)
    if (idx < 64 * NP) {
        int c = idx / NP, p = idx - c * NP;
        unsigned short val = 0;
        int l = -1, local = 0, mul = 0;
        if (p < 2112)      { local = p;        if (local < 2080) { l = 0; mul = 64; } }
        else if (p < 2688) { local = p - 2112; if (local < 528)  { l = 1; mul = 32; } }
        else               { local = p - 2688; if (local < 136)  { l = 2; mul = 16; } }
        if (l >= 0) {
            int u = 0;
            while ((u + 1) * mul - (u + 1) * u / 2 <= local) u++;
            int v = u + (local - (u * mul - u * (u - 1) / 2));
            const float* W = (l == 0) ? W0 : (l == 1) ? W1 : W2;
            float wv = W[(u * mul + v) * 64 + c];
            if (u != v) wv += W[(v * mul + u) * 64 + c];
            val = f2bf((float)(cl_[l] * wv));
        }
        wtf[(size_t)c * NP + p] = val;
        return;
    }
    idx -= 64 * NP;
    // B) wb[5376][64] full symmetrized (diag doubled)
    if (idx < 5376 * 64) {
        int pair = idx >> 6, c = idx & 63;
        int l, w, v, mul;
        if (pair < 4096)      { l = 0; mul = 64; w = pair >> 6;          v = pair & 63; }
        else if (pair < 5120) { l = 1; mul = 32; w = (pair - 4096) >> 5; v = (pair - 4096) & 31; }
        else                  { l = 2; mul = 16; w = (pair - 5120) >> 4; v = (pair - 5120) & 15; }
        const float* W = (l == 0) ? W0 : (l == 1) ? W1 : W2;
        float val;
        if (v == w) val = (float)(2.0 * cl_[l]) * W[(w * mul + w) * 64 + c];
        else        val = (float)cl_[l] * (W[(w * mul + v) * 64 + c] + W[(v * mul + w) * 64 + c]);
        wb[(size_t)pair * 64 + c] = f2bf(val);
        return;
    }
    idx -= 5376 * 64;
    // C) transposed MLP mats
    if (idx < 3 * 4096) {
        int m = idx >> 12, e = idx & 4095;
        int j = e >> 6, k = e & 63;
        const float* A = (m == 0) ? A1 : (m == 1) ? A2 : A3;
        float* dst     = (m == 0) ? a1t : (m == 1) ? a2t : a3t;
        dst[j * 64 + k] = A[k * 64 + j];
        return;
    }
    idx -= 3 * 4096;
    // D) dg2 = colsum(A3)
    if (idx < 64) {
        float s = 0.f;
        for (int k = 0; k < 64; k++) s += A3[k * 64 + idx];
        dg2[idx] = s;
    }
}

// ---------------------------------------------------------------------------
// forward: static pair value from register array
// ---------------------------------------------------------------------------
template <int P, int NX>
__device__ __forceinline__ float pval(const float (&x)[NX]) {
    constexpr int l = PT.l[P];
    if constexpr (l < 0) {
        return 0.f;
    } else if constexpr (l == 0) {
        return x[PT.u[P]] * x[PT.v[P]];
    } else if constexpr (l == 1) {
        constexpr int u = 3 * PT.u[P], v = 3 * PT.v[P];
        return x[u] * x[v] + x[u + 1] * x[v + 1] + x[u + 2] * x[v + 2];
    } else {
        constexpr int u = 5 * PT.u[P], v = 5 * PT.v[P];
        return x[u] * x[v] + x[u + 1] * x[v + 1] + x[u + 2] * x[v + 2]
             + x[u + 3] * x[v + 3] + x[u + 4] * x[v + 4];
    }
}

// one octet (8 pairs) of P -> Pb, fully compile-time indices
template <int CH, int O, int NX>
__device__ __forceinline__ void p_octet(const float (&xr)[NX],
        unsigned short (&Pb)[64][64], int lane)
{
    uint4 w;
    w.x = pack2(pval<CH * 64 + O * 8 + 0, NX>(xr), pval<CH * 64 + O * 8 + 1, NX>(xr));
    w.y = pack2(pval<CH * 64 + O * 8 + 2, NX>(xr), pval<CH * 64 + O * 8 + 3, NX>(xr));
    w.z = pack2(pval<CH * 64 + O * 8 + 4, NX>(xr), pval<CH * 64 + O * 8 + 5, NX>(xr));
    w.w = pack2(pval<CH * 64 + O * 8 + 6, NX>(xr), pval<CH * 64 + O * 8 + 7, NX>(xr));
    *(uint4*)&Pb[lane][(O ^ (lane & 7)) * 8] = w;
}

template <int CH, int NX, int... Os>
__device__ __forceinline__ void p_octets(std::integer_sequence<int, Os...>,
        const float (&xr)[NX], unsigned short (&Pb)[64][64], int lane)
{
    (p_octet<CH, Os, NX>(xr, Pb, lane), ...);
}

// load the 8 B-fragments (wtf) for chunk CH into registers
template <int CH>
__device__ __forceinline__ void load_bfrags(bf8 (&b)[8],
        const unsigned short* __restrict__ wtf, int l15, int quad)
{
    #pragma unroll
    for (int ct = 0; ct < 4; ++ct)
        #pragma unroll
        for (int ks = 0; ks < 2; ++ks)
            b[ct * 2 + ks] = *(const bf8*)(wtf + (size_t)(16 * ct + l15) * NP
                                           + CH * 64 + ks * 32 + quad * 8);
}

// chunk body: pvals -> Pb (wave-private, fence-ordered), frag reads, MFMAs
// using PRE-LOADED B registers (bc, issued one chunk earlier).
template <int CH, int NX>
__device__ __forceinline__ void fwd_body(const float (&xr)[NX],
        unsigned short (&Pb)[64][64], f4 (&acc)[4][4], const bf8 (&bc)[8],
        int lane, int l15, int quad)
{
    p_octets<CH, NX>(std::make_integer_sequence<int, 8>{}, xr, Pb, lane);
    asm volatile("s_waitcnt lgkmcnt(0)" ::: "memory");   // RAW: writes land before reads
    bf8 a[4][2];
    #pragma unroll
    for (int rt = 0; rt < 4; ++rt) {
        int row = 16 * rt + l15;
        #pragma unroll
        for (int ks = 0; ks < 2; ++ks)
            a[rt][ks] = *(const bf8*)&Pb[row][((ks * 4 + quad) ^ (row & 7)) * 8];
    }
    #pragma unroll
    for (int ct = 0; ct < 4; ++ct)
        #pragma unroll
        for (int ks = 0; ks < 2; ++ks)
            #pragma unroll
            for (int rt = 0; rt < 4; ++rt)
                acc[rt][ct] = __builtin_amdgcn_mfma_f32_16x16x32_bf16(
                                  a[rt][ks], bc[ct * 2 + ks], acc[rt][ct], 0, 0, 0);
    asm volatile("" ::: "memory");   // WAR: next chunk's Pb writes stay after these reads
}

// recursion: at chunk I, first ISSUE loads for chunk I+1 (they retire under
// this chunk's pvals+MFMAs), then run body with bc (loaded at level I-1).
template <int B, int N, int I, int NX>
__device__ __forceinline__ void fwd_rec(const float (&xr)[NX],
        unsigned short (&Pb)[64][64], const unsigned short* __restrict__ wtf,
        f4 (&acc)[4][4], bf8 (&bc)[8], int lane, int l15, int quad)
{
    if constexpr (I + 1 < N) {
        bf8 bn[8];
        load_bfrags<B + I + 1>(bn, wtf, l15, quad);          // prefetch next chunk
        fwd_body<B + I, NX>(xr, Pb, acc, bc, lane, l15, quad);
        fwd_rec<B, N, I + 1, NX>(xr, Pb, wtf, acc, bn, lane, l15, quad);
    } else {
        fwd_body<B + I, NX>(xr, Pb, acc, bc, lane, l15, quad);
    }
}

template <int B, int N, int NX>
__device__ __forceinline__ void fwd_run_pf(const float (&xr)[NX],
        unsigned short (&Pb)[64][64], const unsigned short* __restrict__ wtf,
        f4 (&acc)[4][4], int lane, int l15, int quad)
{
    bf8 b0[8];
    load_bfrags<B>(b0, wtf, l15, quad);
    fwd_rec<B, N, 0, NX>(xr, Pb, wtf, acc, b0, lane, l15, quad);
}

// helpers to load per-l x registers
__device__ __forceinline__ void load_x0(float (&x0)[64], const float* xrow) {
    #pragma unroll
    for (int q = 0; q < 16; ++q) *(float4*)&x0[4 * q] = *(const float4*)(xrow + 4 * q);
}
__device__ __forceinline__ void load_x1(float (&x1)[96], const float* xrow) {
    #pragma unroll
    for (int q = 0; q < 24; ++q) *(float4*)&x1[4 * q] = *(const float4*)(xrow + 64 + 4 * q);
}
__device__ __forceinline__ void load_x2(float (&x2)[80], const float* xrow) {
    #pragma unroll
    for (int q = 0; q < 20; ++q) *(float4*)&x2[4 * q] = *(const float4*)(xrow + 160 + 4 * q);
}

// ---------------------------------------------------------------------------
// FUSED fwd + mlp: fwd (r9 shape) reduces h into sact, then mlp body runs
// in-place (wave wv = channel group 16wv, lane = sample).
// ---------------------------------------------------------------------------
__global__ __launch_bounds__(256) void fctp_fwd_mlp(const float* __restrict__ tin,
        const unsigned short* __restrict__ wtf,
        const float* __restrict__ A1, const float* __restrict__ A2,
        const float* __restrict__ a1t, const float* __restrict__ a2t,
        const float* __restrict__ a3t, const float* __restrict__ b1,
        const float* __restrict__ b2, const float* __restrict__ b3,
        const float* __restrict__ dg2,
        float* __restrict__ xout, float* __restrict__ dhout, int n)
{
    __shared__ unsigned short Pb[4][64][64];   // 32KB: private 8KB per wave; reused as reduce scratch
    __shared__ float sact[64][65];             // 16.6KB mlp activation tile
    const int tid = threadIdx.x;
    const int wv = tid >> 6;
    const int lane = tid & 63;
    const int l15 = lane & 15, quad = lane >> 4;
    const int s0 = blockIdx.x * 64;
    const int s = s0 + lane;
    const int sld = (s < n) ? s : (n - 1);
    const bool valid = s < n;
    const float* xrow = tin + (size_t)sld * IRR;
    f4 acc4[4][4];
    #pragma unroll
    for (int rt = 0; rt < 4; ++rt)
        #pragma unroll
        for (int ct = 0; ct < 4; ++ct) acc4[rt][ct] = (f4){0.f, 0.f, 0.f, 0.f};

    // ---- fwd chunk loops (VALU-balanced wave split, B-frag prefetch) ----
    if (wv == 0)      { float x0[64]; load_x0(x0, xrow); fwd_run_pf< 0, 17>(x0, Pb[0], wtf, acc4, lane, l15, quad); }
    else if (wv == 1) { float x0[64]; load_x0(x0, xrow); fwd_run_pf<17, 16>(x0, Pb[1], wtf, acc4, lane, l15, quad); }
    else if (wv == 2) { float x1[96]; load_x1(x1, xrow); fwd_run_pf<33,  9>(x1, Pb[2], wtf, acc4, lane, l15, quad); }
    else              { float x2[80]; load_x2(x2, xrow); fwd_run_pf<42,  3>(x2, Pb[3], wtf, acc4, lane, l15, quad); }

    // ---- cross-wave reduce of acc4 -> sact (h tile), rt-pass at a time ----
    // wave wv sums the ct==wv column stripe: h[16rt+4quad+r][16wv+l15].
    float* red = (float*)Pb;
    #pragma unroll
    for (int rt = 0; rt < 4; ++rt) {
        __syncthreads();   // WAR vs chunk-loop reads (rt=0) / previous pass reads
        #pragma unroll
        for (int ct = 0; ct < 4; ++ct) {
            float4 v = make_float4(acc4[rt][ct][0], acc4[rt][ct][1], acc4[rt][ct][2], acc4[rt][ct][3]);
            *(float4*)&red[(size_t)(wv * 64 + lane) * 20 + ct * 4] = v;
        }
        __syncthreads();
        float4 sum = make_float4(0.f, 0.f, 0.f, 0.f);
        #pragma unroll
        for (int w = 0; w < 4; ++w) {
            float4 v = *(const float4*)&red[(size_t)(w * 64 + lane) * 20 + wv * 4];
            sum.x += v.x; sum.y += v.y; sum.z += v.z; sum.w += v.w;
        }
        #pragma unroll
        for (int r = 0; r < 4; ++r)
            sact[16 * rt + 4 * quad + r][16 * wv + l15] = (&sum.x)[r];
    }
    __syncthreads();   // sact fully populated across waves

    // ---- mlp body (proven mlp4 code; ch0 = wave's channel group) ----
    const int ch0 = __builtin_amdgcn_readfirstlane(wv * 16);
    float acc[16], z1[16], z2[16];

    // L1: z1 = h @ A1.T + b1
    #pragma unroll
    for (int k = 0; k < 16; ++k) acc[k] = b1[ch0 + k];
    #pragma unroll 4
    for (int j = 0; j < 64; ++j) {
        float aj = sact[lane][j];
        const float* r = a1t + j * 64 + ch0;
        #pragma unroll
        for (int k = 0; k < 16; ++k) acc[k] += aj * r[k];
    }
    __syncthreads();               // all reads of h-tile done
    #pragma unroll
    for (int k = 0; k < 16; ++k) {
        float z = acc[k]; z1[k] = z;
        float sg = 1.f / (1.f + __expf(-z));
        sact[lane][ch0 + k] = z * sg;
    }
    __syncthreads();

    // L2: z2 = g1 @ A2.T + b2
    #pragma unroll
    for (int k = 0; k < 16; ++k) acc[k] = b2[ch0 + k];
    #pragma unroll 4
    for (int j = 0; j < 64; ++j) {
        float aj = sact[lane][j];
        const float* r = a2t + j * 64 + ch0;
        #pragma unroll
        for (int k = 0; k < 16; ++k) acc[k] += aj * r[k];
    }
    __syncthreads();
    #pragma unroll
    for (int k = 0; k < 16; ++k) {
        float z = acc[k]; z2[k] = z;
        float sg = 1.f / (1.f + __expf(-z));
        sact[lane][ch0 + k] = z * sg;
    }
    __syncthreads();

    // L3: x = g2 @ A3.T + b3
    #pragma unroll
    for (int k = 0; k < 16; ++k) acc[k] = b3[ch0 + k];
    #pragma unroll 4
    for (int j = 0; j < 64; ++j) {
        float aj = sact[lane][j];
        const float* r = a3t + j * 64 + ch0;
        #pragma unroll
        for (int k = 0; k < 16; ++k) acc[k] += aj * r[k];
    }
    if (valid) {
        float4* xo = (float4*)(xout + (size_t)s * 64 + ch0);
        #pragma unroll
        for (int q = 0; q < 4; ++q)
            xo[q] = make_float4(acc[4 * q], acc[4 * q + 1], acc[4 * q + 2], acc[4 * q + 3]);
    }

    // bwd: dz2 = dg2 * silu'(z2)
    __syncthreads();               // L3 reads of g2 done
    #pragma unroll
    for (int k = 0; k < 16; ++k) {
        float z = z2[k];
        float sg = 1.f / (1.f + __expf(-z));
        sact[lane][ch0 + k] = dg2[ch0 + k] * sg * (1.f + z * (1.f - sg));
    }
    __syncthreads();

    // dg1[j] = sum_k dz2[k] * A2[k][j] ; dz1 = dg1 * silu'(z1)
    #pragma unroll
    for (int k = 0; k < 16; ++k) acc[k] = 0.f;
    #pragma unroll 4
    for (int kk = 0; kk < 64; ++kk) {
        float d = sact[lane][kk];
        const float* r = A2 + kk * 64 + ch0;
        #pragma unroll
        for (int k = 0; k < 16; ++k) acc[k] += d * r[k];
    }
    __syncthreads();
    #pragma unroll
    for (int k = 0; k < 16; ++k) {
        float z = z1[k];
        float sg = 1.f / (1.f + __expf(-z));
        sact[lane][ch0 + k] = acc[k] * sg * (1.f + z * (1.f - sg));
    }
    __syncthreads();

    // dh[i] = sum_j dz1[j] * A1[j][i]
    #pragma unroll
    for (int k = 0; k < 16; ++k) acc[k] = 0.f;
    #pragma unroll 4
    for (int j = 0; j < 64; ++j) {
        float d = sact[lane][j];
        const float* r = A1 + j * 64 + ch0;
        #pragma unroll
        for (int k = 0; k < 16; ++k) acc[k] += d * r[k];
    }
    if (valid) {
        float4* dho = (float4*)(dhout + (size_t)s * 64 + ch0);
        #pragma unroll
        for (int q = 0; q < 4; ++q)
            dho[q] = make_float4(acc[4 * q], acc[4 * q + 1], acc[4 * q + 2], acc[4 * q + 3]);
    }
}

// ---------------------------------------------------------------------------
// backward l0: 4-wave blocks, register-consume, wb A-frags prefetched.
// Grid (nb64, 4). Waves share sample-block & group; wave w does 4 chunks.
// ---------------------------------------------------------------------------
__device__ __forceinline__ void load_awb(int ch, const unsigned short* __restrict__ wb,
        bf8 (&a)[8], int l15, int quad)
{
    #pragma unroll
    for (int rt = 0; rt < 4; ++rt)
        #pragma unroll
        for (int ks = 0; ks < 2; ++ks)
            a[rt * 2 + ks] = *(const bf8*)(wb + (size_t)(ch * 64 + 16 * rt + l15) * 64
                                           + ks * 32 + quad * 8);
}

__device__ __forceinline__ float l0_chunk(const bf8 (&a)[8], const bf8 (&bh)[4][2],
        const float (&xr)[64], int quad)
{
    float p0 = 0.f, p1 = 0.f, p2 = 0.f, p3 = 0.f;   // per-ct partials
    #pragma unroll
    for (int rt = 0; rt < 4; ++rt) {
        f4 dpR[4];
        #pragma unroll
        for (int ct = 0; ct < 4; ++ct) dpR[ct] = (f4){0.f, 0.f, 0.f, 0.f};
        #pragma unroll
        for (int ks = 0; ks < 2; ++ks)
            #pragma unroll
            for (int ct = 0; ct < 4; ++ct)
                dpR[ct] = __builtin_amdgcn_mfma_f32_16x16x32_bf16(
                              a[rt * 2 + ks], bh[ct][ks], dpR[ct], 0, 0, 0);
        #pragma unroll
        for (int r = 0; r < 4; ++r) {
            p0 += dpR[0][r] * xr[ 0 + rt * 4 + r];
            p1 += dpR[1][r] * xr[16 + rt * 4 + r];
            p2 += dpR[2][r] * xr[32 + rt * 4 + r];
            p3 += dpR[3][r] * xr[48 + rt * 4 + r];
        }
    }
    // reduce across the 4 quad-lanes of each sample column
    p0 += __shfl_xor(p0, 16); p0 += __shfl_xor(p0, 32);
    p1 += __shfl_xor(p1, 16); p1 += __shfl_xor(p1, 32);
    p2 += __shfl_xor(p2, 16); p2 += __shfl_xor(p2, 32);
    p3 += __shfl_xor(p3, 16); p3 += __shfl_xor(p3, 32);
    // this lane's sample (= lane = 16*quad+l15) lives in partial[quad]
    return (quad == 0) ? p0 : (quad == 1) ? p1 : (quad == 2) ? p2 : p3;
}

__global__ __launch_bounds__(256) void fctp_bwd_l0(const float* __restrict__ tin,
        const unsigned short* __restrict__ wb, const float* __restrict__ dh,
        float* __restrict__ y, int n)
{
    // 17408B shared: x0 tile f32[64][68] (stride 68 dwords -> xr gather ~2-way).
    // After xr regs are loaded the same space holds the bf16 dh tile.
    __shared__ __align__(16) unsigned char smem[64 * 68 * 4];
    float (*x0t)[68] = (float (*)[68])smem;
    unsigned short (*dhb)[64] = (unsigned short (*)[64])smem;

    const int tid  = threadIdx.x;
    const int wv   = tid >> 6;
    const int lane = tid & 63;
    const int l15 = lane & 15, quad = lane >> 4;
    const int s0 = blockIdx.x * 64;
    const int s = s0 + lane;
    const int sld = (s < n) ? s : (n - 1);
    const bool act = s < n;
    const float* xrow = tin + (size_t)sld * IRR;

    // stage x0 tile: thread writes its sample's [16wv, 16wv+16) slice
    #pragma unroll
    for (int q = 0; q < 4; ++q)
        *(float4*)&x0t[lane][16 * wv + 4 * q] = *(const float4*)(xrow + 16 * wv + 4 * q);
    __syncthreads();
    // permuted consume values: xr[ct*16+rt*4+r] = x0[16ct+l15][16rt+4quad+r]
    float xr[64];
    #pragma unroll
    for (int ct = 0; ct < 4; ++ct)
        #pragma unroll
        for (int rt = 0; rt < 4; ++rt)
            *(float4*)&xr[ct * 16 + rt * 4] =
                *(const float4*)&x0t[16 * ct + l15][16 * rt + 4 * quad];
    __syncthreads();   // x0t reads done before dhb overlay writes
    // stage dh -> bf16 (octet-swizzled): thread writes octets {2wv, 2wv+1}
    {
        const float* dhp = dh + (size_t)sld * 64;
        #pragma unroll
        for (int oo = 0; oo < 2; ++oo) {
            int o = 2 * wv + oo;
            float4 f0 = *(const float4*)(dhp + 8 * o);
            float4 f1 = *(const float4*)(dhp + 8 * o + 4);
            uint4 w = make_uint4(pack2(f0.x, f0.y), pack2(f0.z, f0.w),
                                 pack2(f1.x, f1.y), pack2(f1.z, f1.w));
            *(uint4*)&dhb[lane][(o ^ (lane & 7)) * 8] = w;
        }
    }
    __syncthreads();
    // persistent B-frags: B[k=chan][col=sample] (identical in all 4 waves)
    bf8 bh[4][2];
    #pragma unroll
    for (int ct = 0; ct < 4; ++ct) {
        int row = 16 * ct + l15;
        #pragma unroll
        for (int ks = 0; ks < 2; ++ks)
            bh[ct][ks] = *(const bf8*)&dhb[row][((ks * 4 + quad) ^ (row & 7)) * 8];
    }

    // chunk loop: this wave's 4 chunks, A-frags prefetched 1 chunk ahead
    const int cbase = blockIdx.y * 16 + wv * 4;
    bf8 aA[8], aB[8];
    float res[4];
    load_awb(cbase + 0, wb, aA, l15, quad);
    load_awb(cbase + 1, wb, aB, l15, quad);
    res[0] = l0_chunk(aA, bh, xr, quad);
    load_awb(cbase + 2, wb, aA, l15, quad);
    res[1] = l0_chunk(aB, bh, xr, quad);
    load_awb(cbase + 3, wb, aB, l15, quad);
    res[2] = l0_chunk(aA, bh, xr, quad);
    res[3] = l0_chunk(aB, bh, xr, quad);
    if (act)
        *(float4*)&y[(size_t)s * IRR + cbase] = make_float4(res[0], res[1], res[2], res[3]);
}

// ---------------------------------------------------------------------------
// backward l1/l2: 4 independent waves (4 sample blocks), private dPb each.
// Grid (ceil(nb64/4), 3): y=0,1 -> l1 groups; y=2 -> l2. No barriers.
// ---------------------------------------------------------------------------
__device__ __forceinline__ void bwd_mm(int ch, const unsigned short* __restrict__ wb,
        const bf8 (&bh)[4][2], float (*dPb)[68],
        int lane, int l15, int quad)
{
    f4 dp[4][4];
    #pragma unroll
    for (int rt = 0; rt < 4; ++rt)
        #pragma unroll
        for (int ct = 0; ct < 4; ++ct) dp[rt][ct] = (f4){0.f, 0.f, 0.f, 0.f};
    #pragma unroll
    for (int rt = 0; rt < 4; ++rt) {
        #pragma unroll
        for (int ks = 0; ks < 2; ++ks) {
            bf8 a = *(const bf8*)(wb + (size_t)(ch * 64 + 16 * rt + l15) * 64 + ks * 32 + quad * 8);
            #pragma unroll
            for (int ct = 0; ct < 4; ++ct)
                dp[rt][ct] = __builtin_amdgcn_mfma_f32_16x16x32_bf16(a, bh[ct][ks], dp[rt][ct], 0, 0, 0);
        }
    }
    // dp[rt][ct][r] = dP^T[pair=16rt+4quad+r][sample=16ct+l15] -> dPb[sample][pair]
    #pragma unroll
    for (int rt = 0; rt < 4; ++rt)
        #pragma unroll
        for (int ct = 0; ct < 4; ++ct) {
            float4 v = make_float4(dp[rt][ct][0], dp[rt][ct][1], dp[rt][ct][2], dp[rt][ct][3]);
            *(float4*)&dPb[16 * ct + l15][16 * rt + 4 * quad] = v;
        }
    asm volatile("s_waitcnt lgkmcnt(0)" ::: "memory");   // writes land before consume reads
}

__global__ __launch_bounds__(256) void fctp_bwd_l12(const float* __restrict__ tin,
        const unsigned short* __restrict__ wb, const float* __restrict__ dh,
        float* __restrict__ y, int n)
{
    // per-wave private 17408B region: dPb[64][68] overlaid with dhb staging
    __shared__ __align__(16) unsigned char smem[4][64 * 68 * 4];

    const int tid  = threadIdx.x;
    const int wv   = tid >> 6;
    const int lane = tid & 63;
    const int l15 = lane & 15, quad = lane >> 4;
    float (*dPb)[68] = (float (*)[68])smem[wv];
    unsigned short (*dhb)[64] = (unsigned short (*)[64])smem[wv];

    const int sb = blockIdx.x * 4 + wv;            // this wave's sample block
    const int s0 = sb * 64;
    const int s = s0 + lane;
    const int sld = (s < n) ? s : (n - 1);
    const bool act = s < n;
    // stage dh -> bf16 (octet-swizzled)
    {
        const float* dhp = dh + (size_t)sld * 64;
        #pragma unroll
        for (int o = 0; o < 8; ++o) {
            float4 f0 = *(const float4*)(dhp + 8 * o);
            float4 f1 = *(const float4*)(dhp + 8 * o + 4);
            uint4 w = make_uint4(pack2(f0.x, f0.y), pack2(f0.z, f0.w),
                                 pack2(f1.x, f1.y), pack2(f1.z, f1.w));
            *(uint4*)&dhb[lane][(o ^ (lane & 7)) * 8] = w;
        }
    }
    asm volatile("s_waitcnt lgkmcnt(0)" ::: "memory");   // wave-local: staging visible
    bf8 bh[4][2];
    #pragma unroll
    for (int ct = 0; ct < 4; ++ct) {
        int row = 16 * ct + l15;
        #pragma unroll
        for (int ks = 0; ks < 2; ++ks)
            bh[ct][ks] = *(const bf8*)&dhb[row][((ks * 4 + quad) ^ (row & 7)) * 8];
    }
    asm volatile("" ::: "memory");   // dhb reads precede dPb overlay writes
    const float* xrow = tin + (size_t)sld * IRR;
    float* yrow = y + (size_t)sld * IRR;

    if (blockIdx.y < 2) {
        // l1: chunks 64+[8by, 8by+8), w = 2c1+wi, local col = wi*32+v
        float x1[96];
        #pragma unroll
        for (int q = 0; q < 24; ++q) *(float4*)&x1[4 * q] = *(const float4*)(xrow + 64 + 4 * q);
        const int cbase = blockIdx.y * 8;
        for (int i = 0; i < 8; ++i) {
            const int c1 = cbase + i;
            bwd_mm(64 + c1, wb, bh, dPb, lane, l15, quad);
            float r[2][3] = {{0.f, 0.f, 0.f}, {0.f, 0.f, 0.f}};
            #pragma unroll
            for (int v = 0; v < 32; v += 4) {
                float4 dA = *(const float4*)&dPb[lane][v];
                float4 dB = *(const float4*)&dPb[lane][32 + v];
                #pragma unroll
                for (int vv = 0; vv < 4; ++vv) {
                    float da = (&dA.x)[vv], db = (&dB.x)[vv];
                    #pragma unroll
                    for (int m = 0; m < 3; ++m) {
                        r[0][m] += da * x1[3 * (v + vv) + m];
                        r[1][m] += db * x1[3 * (v + vv) + m];
                    }
                }
            }
            if (act) {
                #pragma unroll
                for (int wi = 0; wi < 2; ++wi)
                    #pragma unroll
                    for (int m = 0; m < 3; ++m)
                        yrow[64 + (2 * c1 + wi) * 3 + m] = r[wi][m];
            }
        }
    } else {
        // l2: chunks 80..83, w = 4c2+t, local col = t*16+v
        float x2[80];
        #pragma unroll
        for (int q = 0; q < 20; ++q) *(float4*)&x2[4 * q] = *(const float4*)(xrow + 160 + 4 * q);
        for (int c2 = 0; c2 < 4; ++c2) {
            bwd_mm(80 + c2, wb, bh, dPb, lane, l15, quad);
            float r[4][5] = {};
            #pragma unroll
            for (int t = 0; t < 4; ++t) {
                #pragma unroll
                for (int v = 0; v < 16; v += 4) {
                    float4 d = *(const float4*)&dPb[lane][t * 16 + v];
                    #pragma unroll
                    for (int vv = 0; vv < 4; ++vv)
                        #pragma unroll
                        for (int m = 0; m < 5; ++m)
                            r[t][m] += (&d.x)[vv] * x2[5 * (v + vv) + m];
                }
            }
            if (act) {
                #pragma unroll
                for (int t = 0; t < 4; ++t)
                    #pragma unroll
                    for (int m = 0; m < 5; ++m)
                        yrow[160 + (4 * c2 + t) * 5 + m] = r[t][m];
            }
        }
    }
}

// ---------------------------------------------------------------------------
extern "C" void kernel_launch(void* const* d_in, const int* in_sizes, int n_in,
                              void* d_out, int out_size, void* d_ws, size_t ws_size,
                              hipStream_t stream)
{
    const float* tin = (const float*)d_in[0];
    const float* W0  = (const float*)d_in[1];
    const float* W1  = (const float*)d_in[2];
    const float* W2  = (const float*)d_in[3];
    const float* A1  = (const float*)d_in[4];
    const float* b1  = (const float*)d_in[5];
    const float* A2  = (const float*)d_in[6];
    const float* b2  = (const float*)d_in[7];
    const float* A3  = (const float*)d_in[8];
    const float* b3  = (const float*)d_in[9];
    float* out = (float*)d_out;
    char* ws   = (char*)d_ws;
    const int n = in_sizes[0] / IRR;

    unsigned short* wtf = (unsigned short*)(ws + B_WTF);
    unsigned short* wb  = (unsigned short*)(ws + B_WB);
    float* a1t  = (float*)(ws + B_A1T);
    float* a2t  = (float*)(ws + B_A2T);
    float* a3t  = (float*)(ws + B_A3T);
    float* dg2  = (float*)(ws + B_DG2);
    float* dh   = (float*)(ws + B_H);
    float* xout = out;
    float* yout = out + (size_t)n * 64;

    const int total_prep = 64 * NP + 5376 * 64 + 3 * 4096 + 64;
    prep_kernel<<<(total_prep + 255) / 256, 256, 0, stream>>>(W0, W1, W2, A1, A2, A3,
                                                              wtf, wb, a1t, a2t, a3t, dg2);
    const int nb64 = (n + 63) / 64;
    fctp_fwd_mlp<<<nb64, 256, 0, stream>>>(tin, wtf, A1, A2, a1t, a2t, a3t,
                                           b1, b2, b3, dg2, xout, dh, n);
    fctp_bwd_l0<<<dim3(nb64, 4), 256, 0, stream>>>(tin, wb, dh, yout, n);
    fctp_bwd_l12<<<dim3((nb64 + 3) / 4, 3), 256, 0, stream>>>(tin, wb, dh, yout, n);
}

// Round 12
// 323.883 us; speedup vs baseline: 1.1579x; 1.1579x over previous
//
#include <hip/hip_runtime.h>
#include <math.h>
#include <utility>

// ---------------------------------------------------------------------------
// FCTP(64x0e+32x1o+16x2e -> 64x0e) + 3-layer SiLU MLP, fwd + input-grad.
//   r12 = r9 structure (best-known 329us; r10 split and r11 fusion both
//   regressed) + fwd wave REBALANCE: chunk counts 17/16/9/3 -> 12/12/12/9
//   (w2 runs l0 tail then l2; x0/x2 live ranges are sequential so VGPR flat).
//   fwd: 4-wave WGs, private Pb, B-frag prefetch, 4-way LDS reduce -> h.
//   mlp: standalone channel-split 4-wave kernel (fusion was neutral-minus).
//   bwd_l0 : 4-wave WGs, register-consume, padded x0 tile, wb prefetch.
//   bwd_l12: independent-wave private-dPb LDS transpose.
// ---------------------------------------------------------------------------

typedef short bf8 __attribute__((ext_vector_type(8)));
typedef float f4 __attribute__((ext_vector_type(4)));

constexpr int IRR = 240;

// padded fwd pair enumeration: l0: [0,2112) real 2080 ; l1: [2112,2688) real 528
// l2: [2688,2880) real 136.  45 chunks of 64.
constexpr int NP = 2880;

struct PTab { short u[NP]; short v[NP]; signed char l[NP]; };
constexpr PTab build_ptab() {
    PTab t{}; int p = 0;
    for (int u = 0; u < 64; u++) for (int v = u; v < 64; v++) { t.u[p]=(short)u; t.v[p]=(short)v; t.l[p]=0; p++; }
    while (p < 2112) { t.l[p] = -1; p++; }
    for (int u = 0; u < 32; u++) for (int v = u; v < 32; v++) { t.u[p]=(short)u; t.v[p]=(short)v; t.l[p]=1; p++; }
    while (p < 2688) { t.l[p] = -1; p++; }
    for (int u = 0; u < 16; u++) for (int v = u; v < 16; v++) { t.u[p]=(short)u; t.v[p]=(short)v; t.l[p]=2; p++; }
    while (p < NP)   { t.l[p] = -1; p++; }
    return t;
}
constexpr PTab PT = build_ptab();

// ws layout (bytes)
constexpr size_t B_WTF = 0;                       // bf16 [64 chan][2880 pair]
constexpr size_t B_WB  = (size_t)64 * NP * 2;     // 368640 : bf16 [5376 pair][64 chan]
constexpr size_t B_A1T = B_WB + (size_t)5376 * 64 * 2;   // 1056768
constexpr size_t B_A2T = B_A1T + 16384;
constexpr size_t B_A3T = B_A2T + 16384;
constexpr size_t B_DG2 = B_A3T + 16384;
constexpr size_t B_H   = B_DG2 + 256;             // h[n*64] then dh[n*64]

__device__ __forceinline__ unsigned short f2bf(float x) {
    unsigned int u = __float_as_uint(x);
    return (unsigned short)((u + 0x7fffu + ((u >> 16) & 1u)) >> 16);
}
__device__ __forceinline__ unsigned pack2(float a, float b) {   // -> [bf16(a), bf16(b)]
    unsigned ua = __float_as_uint(a) + 0x8000u;   // round-half-up (0.5 ulp)
    unsigned ub = __float_as_uint(b) + 0x8000u;
    return __builtin_amdgcn_perm(ub, ua, 0x07060302u);
}

// ---------------------------------------------------------------------------
__global__ void prep_kernel(const float* __restrict__ W0, const float* __restrict__ W1,
                            const float* __restrict__ W2, const float* __restrict__ A1,
                            const float* __restrict__ A2, const float* __restrict__ A3,
                            unsigned short* __restrict__ wtf, unsigned short* __restrict__ wb,
                            float* __restrict__ a1t, float* __restrict__ a2t,
                            float* __restrict__ a3t, float* __restrict__ dg2)
{
    int idx = blockIdx.x * blockDim.x + threadIdx.x;
    const double c0 = 1.0 / sqrt(5376.0);
    const double cl_[3] = { c0, c0 / sqrt(3.0), c0 / sqrt(5.0) };
    // A) wtf[chan][2880] (padded fwd table, zero pads)
    if (idx < 64 * NP) {
        int c = idx / NP, p = idx - c * NP;
        unsigned short val = 0;
        int l = -1, local = 0, mul = 0;
        if (p < 2112)      { local = p;        if (local < 2080) { l = 0; mul = 64; } }
        else if (p < 2688) { local = p - 2112; if (local < 528)  { l = 1; mul = 32; } }
        else               { local = p - 2688; if (local < 136)  { l = 2; mul = 16; } }
        if (l >= 0) {
            int u = 0;
            while ((u + 1) * mul - (u + 1) * u / 2 <= local) u++;
            int v = u + (local - (u * mul - u * (u - 1) / 2));
            const float* W = (l == 0) ? W0 : (l == 1) ? W1 : W2;
            float wv = W[(u * mul + v) * 64 + c];
            if (u != v) wv += W[(v * mul + u) * 64 + c];
            val = f2bf((float)(cl_[l] * wv));
        }
        wtf[(size_t)c * NP + p] = val;
        return;
    }
    idx -= 64 * NP;
    // B) wb[5376][64] full symmetrized (diag doubled)
    if (idx < 5376 * 64) {
        int pair = idx >> 6, c = idx & 63;
        int l, w, v, mul;
        if (pair < 4096)      { l = 0; mul = 64; w = pair >> 6;          v = pair & 63; }
        else if (pair < 5120) { l = 1; mul = 32; w = (pair - 4096) >> 5; v = (pair - 4096) & 31; }
        else                  { l = 2; mul = 16; w = (pair - 5120) >> 4; v = (pair - 5120) & 15; }
        const float* W = (l == 0) ? W0 : (l == 1) ? W1 : W2;
        float val;
        if (v == w) val = (float)(2.0 * cl_[l]) * W[(w * mul + w) * 64 + c];
        else        val = (float)cl_[l] * (W[(w * mul + v) * 64 + c] + W[(v * mul + w) * 64 + c]);
        wb[(size_t)pair * 64 + c] = f2bf(val);
        return;
    }
    idx -= 5376 * 64;
    // C) transposed MLP mats
    if (idx < 3 * 4096) {
        int m = idx >> 12, e = idx & 4095;
        int j = e >> 6, k = e & 63;
        const float* A = (m == 0) ? A1 : (m == 1) ? A2 : A3;
        float* dst     = (m == 0) ? a1t : (m == 1) ? a2t : a3t;
        dst[j * 64 + k] = A[k * 64 + j];
        return;
    }
    idx -= 3 * 4096;
    // D) dg2 = colsum(A3)
    if (idx < 64) {
        float s = 0.f;
        for (int k = 0; k < 64; k++) s += A3[k * 64 + idx];
        dg2[idx] = s;
    }
}

// ---------------------------------------------------------------------------
// forward: static pair value from register array
// ---------------------------------------------------------------------------
template <int P, int NX>
__device__ __forceinline__ float pval(const float (&x)[NX]) {
    constexpr int l = PT.l[P];
    if constexpr (l < 0) {
        return 0.f;
    } else if constexpr (l == 0) {
        return x[PT.u[P]] * x[PT.v[P]];
    } else if constexpr (l == 1) {
        constexpr int u = 3 * PT.u[P], v = 3 * PT.v[P];
        return x[u] * x[v] + x[u + 1] * x[v + 1] + x[u + 2] * x[v + 2];
    } else {
        constexpr int u = 5 * PT.u[P], v = 5 * PT.v[P];
        return x[u] * x[v] + x[u + 1] * x[v + 1] + x[u + 2] * x[v + 2]
             + x[u + 3] * x[v + 3] + x[u + 4] * x[v + 4];
    }
}

// one octet (8 pairs) of P -> Pb, fully compile-time indices
template <int CH, int O, int NX>
__device__ __forceinline__ void p_octet(const float (&xr)[NX],
        unsigned short (&Pb)[64][64], int lane)
{
    uint4 w;
    w.x = pack2(pval<CH * 64 + O * 8 + 0, NX>(xr), pval<CH * 64 + O * 8 + 1, NX>(xr));
    w.y = pack2(pval<CH * 64 + O * 8 + 2, NX>(xr), pval<CH * 64 + O * 8 + 3, NX>(xr));
    w.z = pack2(pval<CH * 64 + O * 8 + 4, NX>(xr), pval<CH * 64 + O * 8 + 5, NX>(xr));
    w.w = pack2(pval<CH * 64 + O * 8 + 6, NX>(xr), pval<CH * 64 + O * 8 + 7, NX>(xr));
    *(uint4*)&Pb[lane][(O ^ (lane & 7)) * 8] = w;
}

template <int CH, int NX, int... Os>
__device__ __forceinline__ void p_octets(std::integer_sequence<int, Os...>,
        const float (&xr)[NX], unsigned short (&Pb)[64][64], int lane)
{
    (p_octet<CH, Os, NX>(xr, Pb, lane), ...);
}

// load the 8 B-fragments (wtf) for chunk CH into registers
template <int CH>
__device__ __forceinline__ void load_bfrags(bf8 (&b)[8],
        const unsigned short* __restrict__ wtf, int l15, int quad)
{
    #pragma unroll
    for (int ct = 0; ct < 4; ++ct)
        #pragma unroll
        for (int ks = 0; ks < 2; ++ks)
            b[ct * 2 + ks] = *(const bf8*)(wtf + (size_t)(16 * ct + l15) * NP
                                           + CH * 64 + ks * 32 + quad * 8);
}

// chunk body: pvals -> Pb (wave-private, fence-ordered), frag reads, MFMAs
// using PRE-LOADED B registers (bc, issued one chunk earlier).
template <int CH, int NX>
__device__ __forceinline__ void fwd_body(const float (&xr)[NX],
        unsigned short (&Pb)[64][64], f4 (&acc)[4][4], const bf8 (&bc)[8],
        int lane, int l15, int quad)
{
    p_octets<CH, NX>(std::make_integer_sequence<int, 8>{}, xr, Pb, lane);
    asm volatile("s_waitcnt lgkmcnt(0)" ::: "memory");   // RAW: writes land before reads
    bf8 a[4][2];
    #pragma unroll
    for (int rt = 0; rt < 4; ++rt) {
        int row = 16 * rt + l15;
        #pragma unroll
        for (int ks = 0; ks < 2; ++ks)
            a[rt][ks] = *(const bf8*)&Pb[row][((ks * 4 + quad) ^ (row & 7)) * 8];
    }
    #pragma unroll
    for (int ct = 0; ct < 4; ++ct)
        #pragma unroll
        for (int ks = 0; ks < 2; ++ks)
            #pragma unroll
            for (int rt = 0; rt < 4; ++rt)
                acc[rt][ct] = __builtin_amdgcn_mfma_f32_16x16x32_bf16(
                                  a[rt][ks], bc[ct * 2 + ks], acc[rt][ct], 0, 0, 0);
    asm volatile("" ::: "memory");   // WAR: next chunk's Pb writes stay after these reads
}

// recursion: at chunk I, first ISSUE loads for chunk I+1 (they retire under
// this chunk's pvals+MFMAs), then run body with bc (loaded at level I-1).
template <int B, int N, int I, int NX>
__device__ __forceinline__ void fwd_rec(const float (&xr)[NX],
        unsigned short (&Pb)[64][64], const unsigned short* __restrict__ wtf,
        f4 (&acc)[4][4], bf8 (&bc)[8], int lane, int l15, int quad)
{
    if constexpr (I + 1 < N) {
        bf8 bn[8];
        load_bfrags<B + I + 1>(bn, wtf, l15, quad);          // prefetch next chunk
        fwd_body<B + I, NX>(xr, Pb, acc, bc, lane, l15, quad);
        fwd_rec<B, N, I + 1, NX>(xr, Pb, wtf, acc, bn, lane, l15, quad);
    } else {
        fwd_body<B + I, NX>(xr, Pb, acc, bc, lane, l15, quad);
    }
}

template <int B, int N, int NX>
__device__ __forceinline__ void fwd_run_pf(const float (&xr)[NX],
        unsigned short (&Pb)[64][64], const unsigned short* __restrict__ wtf,
        f4 (&acc)[4][4], int lane, int l15, int quad)
{
    bf8 b0[8];
    load_bfrags<B>(b0, wtf, l15, quad);
    fwd_rec<B, N, 0, NX>(xr, Pb, wtf, acc, b0, lane, l15, quad);
}

// helpers to load per-l x registers
__device__ __forceinline__ void load_x0(float (&x0)[64], const float* xrow) {
    #pragma unroll
    for (int q = 0; q < 16; ++q) *(float4*)&x0[4 * q] = *(const float4*)(xrow + 4 * q);
}
__device__ __forceinline__ void load_x1(float (&x1)[96], const float* xrow) {
    #pragma unroll
    for (int q = 0; q < 24; ++q) *(float4*)&x1[4 * q] = *(const float4*)(xrow + 64 + 4 * q);
}
__device__ __forceinline__ void load_x2(float (&x2)[80], const float* xrow) {
    #pragma unroll
    for (int q = 0; q < 20; ++q) *(float4*)&x2[4 * q] = *(const float4*)(xrow + 160 + 4 * q);
}

__global__ __launch_bounds__(256) void fctp_fwd4(const float* __restrict__ tin,
        const unsigned short* __restrict__ wtf, float* __restrict__ h, int n)
{
    __shared__ unsigned short Pb[4][64][64];   // 32KB: private 8KB per wave; reused as reduce scratch
    const int tid = threadIdx.x;
    const int wv = tid >> 6;
    const int lane = tid & 63;
    const int l15 = lane & 15, quad = lane >> 4;
    const int s0 = blockIdx.x * 64;
    const int s = s0 + lane;
    const int sld = (s < n) ? s : (n - 1);
    const float* xrow = tin + (size_t)sld * IRR;
    f4 acc[4][4];
    #pragma unroll
    for (int rt = 0; rt < 4; ++rt)
        #pragma unroll
        for (int ct = 0; ct < 4; ++ct) acc[rt][ct] = (f4){0.f, 0.f, 0.f, 0.f};

    // chunk split, count-balanced 12/12/12/9 (critical path 17 -> 12):
    // w0: l0[0,12)  w1: l0[12,24)  w2: l0[24,33) then l2[42,45)  w3: l1[33,42)
    // (w2's x0 live range ends before x2 loads -> compiler reuses the regs)
    if (wv == 0) {
        float x0[64]; load_x0(x0, xrow);
        fwd_run_pf< 0, 12>(x0, Pb[0], wtf, acc, lane, l15, quad);
    } else if (wv == 1) {
        float x0[64]; load_x0(x0, xrow);
        fwd_run_pf<12, 12>(x0, Pb[1], wtf, acc, lane, l15, quad);
    } else if (wv == 2) {
        {
            float x0[64]; load_x0(x0, xrow);
            fwd_run_pf<24, 9>(x0, Pb[2], wtf, acc, lane, l15, quad);
        }
        {
            float x2[80]; load_x2(x2, xrow);
            fwd_run_pf<42, 3>(x2, Pb[2], wtf, acc, lane, l15, quad);
        }
    } else {
        float x1[96]; load_x1(x1, xrow);
        fwd_run_pf<33, 9>(x1, Pb[3], wtf, acc, lane, l15, quad);
    }

    // cross-wave reduce of acc, rt-pass at a time. red stride 20 dwords (bank spread).
    // wave wv sums & stores the ct==wv column stripe: h[s0+16rt+4quad+r][16wv+l15].
    float* red = (float*)Pb;
    #pragma unroll
    for (int rt = 0; rt < 4; ++rt) {
        __syncthreads();   // WAR vs chunk-loop reads (rt=0) / previous pass reads
        #pragma unroll
        for (int ct = 0; ct < 4; ++ct) {
            float4 v = make_float4(acc[rt][ct][0], acc[rt][ct][1], acc[rt][ct][2], acc[rt][ct][3]);
            *(float4*)&red[(size_t)(wv * 64 + lane) * 20 + ct * 4] = v;
        }
        __syncthreads();
        float4 sum = make_float4(0.f, 0.f, 0.f, 0.f);
        #pragma unroll
        for (int w = 0; w < 4; ++w) {
            float4 v = *(const float4*)&red[(size_t)(w * 64 + lane) * 20 + wv * 4];
            sum.x += v.x; sum.y += v.y; sum.z += v.z; sum.w += v.w;
        }
        #pragma unroll
        for (int r = 0; r < 4; ++r) {
            int row = s0 + 16 * rt + 4 * quad + r;
            if (row < n) h[(size_t)row * 64 + 16 * wv + l15] = (&sum.x)[r];
        }
    }
}

// ---------------------------------------------------------------------------
// backward l0: 4-wave blocks, register-consume, wb A-frags prefetched.
// Grid (nb64, 4). Waves share sample-block & group; wave w does 4 chunks.
// ---------------------------------------------------------------------------
__device__ __forceinline__ void load_awb(int ch, const unsigned short* __restrict__ wb,
        bf8 (&a)[8], int l15, int quad)
{
    #pragma unroll
    for (int rt = 0; rt < 4; ++rt)
        #pragma unroll
        for (int ks = 0; ks < 2; ++ks)
            a[rt * 2 + ks] = *(const bf8*)(wb + (size_t)(ch * 64 + 16 * rt + l15) * 64
                                           + ks * 32 + quad * 8);
}

__device__ __forceinline__ float l0_chunk(const bf8 (&a)[8], const bf8 (&bh)[4][2],
        const float (&xr)[64], int quad)
{
    float p0 = 0.f, p1 = 0.f, p2 = 0.f, p3 = 0.f;   // per-ct partials
    #pragma unroll
    for (int rt = 0; rt < 4; ++rt) {
        f4 dpR[4];
        #pragma unroll
        for (int ct = 0; ct < 4; ++ct) dpR[ct] = (f4){0.f, 0.f, 0.f, 0.f};
        #pragma unroll
        for (int ks = 0; ks < 2; ++ks)
            #pragma unroll
            for (int ct = 0; ct < 4; ++ct)
                dpR[ct] = __builtin_amdgcn_mfma_f32_16x16x32_bf16(
                              a[rt * 2 + ks], bh[ct][ks], dpR[ct], 0, 0, 0);
        #pragma unroll
        for (int r = 0; r < 4; ++r) {
            p0 += dpR[0][r] * xr[ 0 + rt * 4 + r];
            p1 += dpR[1][r] * xr[16 + rt * 4 + r];
            p2 += dpR[2][r] * xr[32 + rt * 4 + r];
            p3 += dpR[3][r] * xr[48 + rt * 4 + r];
        }
    }
    // reduce across the 4 quad-lanes of each sample column
    p0 += __shfl_xor(p0, 16); p0 += __shfl_xor(p0, 32);
    p1 += __shfl_xor(p1, 16); p1 += __shfl_xor(p1, 32);
    p2 += __shfl_xor(p2, 16); p2 += __shfl_xor(p2, 32);
    p3 += __shfl_xor(p3, 16); p3 += __shfl_xor(p3, 32);
    // this lane's sample (= lane = 16*quad+l15) lives in partial[quad]
    return (quad == 0) ? p0 : (quad == 1) ? p1 : (quad == 2) ? p2 : p3;
}

__global__ __launch_bounds__(256) void fctp_bwd_l0(const float* __restrict__ tin,
        const unsigned short* __restrict__ wb, const float* __restrict__ dh,
        float* __restrict__ y, int n)
{
    // 17408B shared: x0 tile f32[64][68] (stride 68 dwords -> xr gather ~2-way).
    // After xr regs are loaded the same space holds the bf16 dh tile.
    __shared__ __align__(16) unsigned char smem[64 * 68 * 4];
    float (*x0t)[68] = (float (*)[68])smem;
    unsigned short (*dhb)[64] = (unsigned short (*)[64])smem;

    const int tid  = threadIdx.x;
    const int wv   = tid >> 6;
    const int lane = tid & 63;
    const int l15 = lane & 15, quad = lane >> 4;
    const int s0 = blockIdx.x * 64;
    const int s = s0 + lane;
    const int sld = (s < n) ? s : (n - 1);
    const bool act = s < n;
    const float* xrow = tin + (size_t)sld * IRR;

    // stage x0 tile: thread writes its sample's [16wv, 16wv+16) slice
    #pragma unroll
    for (int q = 0; q < 4; ++q)
        *(float4*)&x0t[lane][16 * wv + 4 * q] = *(const float4*)(xrow + 16 * wv + 4 * q);
    __syncthreads();
    // permuted consume values: xr[ct*16+rt*4+r] = x0[16ct+l15][16rt+4quad+r]
    float xr[64];
    #pragma unroll
    for (int ct = 0; ct < 4; ++ct)
        #pragma unroll
        for (int rt = 0; rt < 4; ++rt)
            *(float4*)&xr[ct * 16 + rt * 4] =
                *(const float4*)&x0t[16 * ct + l15][16 * rt + 4 * quad];
    __syncthreads();   // x0t reads done before dhb overlay writes
    // stage dh -> bf16 (octet-swizzled): thread writes octets {2wv, 2wv+1}
    {
        const float* dhp = dh + (size_t)sld * 64;
        #pragma unroll
        for (int oo = 0; oo < 2; ++oo) {
            int o = 2 * wv + oo;
            float4 f0 = *(const float4*)(dhp + 8 * o);
            float4 f1 = *(const float4*)(dhp + 8 * o + 4);
            uint4 w = make_uint4(pack2(f0.x, f0.y), pack2(f0.z, f0.w),
                                 pack2(f1.x, f1.y), pack2(f1.z, f1.w));
            *(uint4*)&dhb[lane][(o ^ (lane & 7)) * 8] = w;
        }
    }
    __syncthreads();
    // persistent B-frags: B[k=chan][col=sample] (identical in all 4 waves)
    bf8 bh[4][2];
    #pragma unroll
    for (int ct = 0; ct < 4; ++ct) {
        int row = 16 * ct + l15;
        #pragma unroll
        for (int ks = 0; ks < 2; ++ks)
            bh[ct][ks] = *(const bf8*)&dhb[row][((ks * 4 + quad) ^ (row & 7)) * 8];
    }

    // chunk loop: this wave's 4 chunks, A-frags prefetched 1 chunk ahead
    const int cbase = blockIdx.y * 16 + wv * 4;
    bf8 aA[8], aB[8];
    float res[4];
    load_awb(cbase + 0, wb, aA, l15, quad);
    load_awb(cbase + 1, wb, aB, l15, quad);
    res[0] = l0_chunk(aA, bh, xr, quad);
    load_awb(cbase + 2, wb, aA, l15, quad);
    res[1] = l0_chunk(aB, bh, xr, quad);
    load_awb(cbase + 3, wb, aB, l15, quad);
    res[2] = l0_chunk(aA, bh, xr, quad);
    res[3] = l0_chunk(aB, bh, xr, quad);
    if (act)
        *(float4*)&y[(size_t)s * IRR + cbase] = make_float4(res[0], res[1], res[2], res[3]);
}

// ---------------------------------------------------------------------------
// backward l1/l2: 4 independent waves (4 sample blocks), private dPb each.
// Grid (ceil(nb64/4), 3): y=0,1 -> l1 groups; y=2 -> l2. No barriers.
// ---------------------------------------------------------------------------
__device__ __forceinline__ void bwd_mm(int ch, const unsigned short* __restrict__ wb,
        const bf8 (&bh)[4][2], float (*dPb)[68],
        int lane, int l15, int quad)
{
    f4 dp[4][4];
    #pragma unroll
    for (int rt = 0; rt < 4; ++rt)
        #pragma unroll
        for (int ct = 0; ct < 4; ++ct) dp[rt][ct] = (f4){0.f, 0.f, 0.f, 0.f};
    #pragma unroll
    for (int rt = 0; rt < 4; ++rt) {
        #pragma unroll
        for (int ks = 0; ks < 2; ++ks) {
            bf8 a = *(const bf8*)(wb + (size_t)(ch * 64 + 16 * rt + l15) * 64 + ks * 32 + quad * 8);
            #pragma unroll
            for (int ct = 0; ct < 4; ++ct)
                dp[rt][ct] = __builtin_amdgcn_mfma_f32_16x16x32_bf16(a, bh[ct][ks], dp[rt][ct], 0, 0, 0);
        }
    }
    // dp[rt][ct][r] = dP^T[pair=16rt+4quad+r][sample=16ct+l15] -> dPb[sample][pair]
    #pragma unroll
    for (int rt = 0; rt < 4; ++rt)
        #pragma unroll
        for (int ct = 0; ct < 4; ++ct) {
            float4 v = make_float4(dp[rt][ct][0], dp[rt][ct][1], dp[rt][ct][2], dp[rt][ct][3]);
            *(float4*)&dPb[16 * ct + l15][16 * rt + 4 * quad] = v;
        }
    asm volatile("s_waitcnt lgkmcnt(0)" ::: "memory");   // writes land before consume reads
}

__global__ __launch_bounds__(256) void fctp_bwd_l12(const float* __restrict__ tin,
        const unsigned short* __restrict__ wb, const float* __restrict__ dh,
        float* __restrict__ y, int n)
{
    // per-wave private 17408B region: dPb[64][68] overlaid with dhb staging
    __shared__ __align__(16) unsigned char smem[4][64 * 68 * 4];

    const int tid  = threadIdx.x;
    const int wv   = tid >> 6;
    const int lane = tid & 63;
    const int l15 = lane & 15, quad = lane >> 4;
    float (*dPb)[68] = (float (*)[68])smem[wv];
    unsigned short (*dhb)[64] = (unsigned short (*)[64])smem[wv];

    const int sb = blockIdx.x * 4 + wv;            // this wave's sample block
    const int s0 = sb * 64;
    const int s = s0 + lane;
    const int sld = (s < n) ? s : (n - 1);
    const bool act = s < n;
    // stage dh -> bf16 (octet-swizzled)
    {
        const float* dhp = dh + (size_t)sld * 64;
        #pragma unroll
        for (int o = 0; o < 8; ++o) {
            float4 f0 = *(const float4*)(dhp + 8 * o);
            float4 f1 = *(const float4*)(dhp + 8 * o + 4);
            uint4 w = make_uint4(pack2(f0.x, f0.y), pack2(f0.z, f0.w),
                                 pack2(f1.x, f1.y), pack2(f1.z, f1.w));
            *(uint4*)&dhb[lane][(o ^ (lane & 7)) * 8] = w;
        }
    }
    asm volatile("s_waitcnt lgkmcnt(0)" ::: "memory");   // wave-local: staging visible
    bf8 bh[4][2];
    #pragma unroll
    for (int ct = 0; ct < 4; ++ct) {
        int row = 16 * ct + l15;
        #pragma unroll
        for (int ks = 0; ks < 2; ++ks)
            bh[ct][ks] = *(const bf8*)&dhb[row][((ks * 4 + quad) ^ (row & 7)) * 8];
    }
    asm volatile("" ::: "memory");   // dhb reads precede dPb overlay writes
    const float* xrow = tin + (size_t)sld * IRR;
    float* yrow = y + (size_t)sld * IRR;

    if (blockIdx.y < 2) {
        // l1: chunks 64+[8by, 8by+8), w = 2c1+wi, local col = wi*32+v
        float x1[96];
        #pragma unroll
        for (int q = 0; q < 24; ++q) *(float4*)&x1[4 * q] = *(const float4*)(xrow + 64 + 4 * q);
        const int cbase = blockIdx.y * 8;
        for (int i = 0; i < 8; ++i) {
            const int c1 = cbase + i;
            bwd_mm(64 + c1, wb, bh, dPb, lane, l15, quad);
            float r[2][3] = {{0.f, 0.f, 0.f}, {0.f, 0.f, 0.f}};
            #pragma unroll
            for (int v = 0; v < 32; v += 4) {
                float4 dA = *(const float4*)&dPb[lane][v];
                float4 dB = *(const float4*)&dPb[lane][32 + v];
                #pragma unroll
                for (int vv = 0; vv < 4; ++vv) {
                    float da = (&dA.x)[vv], db = (&dB.x)[vv];
                    #pragma unroll
                    for (int m = 0; m < 3; ++m) {
                        r[0][m] += da * x1[3 * (v + vv) + m];
                        r[1][m] += db * x1[3 * (v + vv) + m];
                    }
                }
            }
            if (act) {
                #pragma unroll
                for (int wi = 0; wi < 2; ++wi)
                    #pragma unroll
                    for (int m = 0; m < 3; ++m)
                        yrow[64 + (2 * c1 + wi) * 3 + m] = r[wi][m];
            }
        }
    } else {
        // l2: chunks 80..83, w = 4c2+t, local col = t*16+v
        float x2[80];
        #pragma unroll
        for (int q = 0; q < 20; ++q) *(float4*)&x2[4 * q] = *(const float4*)(xrow + 160 + 4 * q);
        for (int c2 = 0; c2 < 4; ++c2) {
            bwd_mm(80 + c2, wb, bh, dPb, lane, l15, quad);
            float r[4][5] = {};
            #pragma unroll
            for (int t = 0; t < 4; ++t) {
                #pragma unroll
                for (int v = 0; v < 16; v += 4) {
                    float4 d = *(const float4*)&dPb[lane][t * 16 + v];
                    #pragma unroll
                    for (int vv = 0; vv < 4; ++vv)
                        #pragma unroll
                        for (int m = 0; m < 5; ++m)
                            r[t][m] += (&d.x)[vv] * x2[5 * (v + vv) + m];
                }
            }
            if (act) {
                #pragma unroll
                for (int t = 0; t < 4; ++t)
                    #pragma unroll
                    for (int m = 0; m < 5; ++m)
                        yrow[160 + (4 * c2 + t) * 5 + m] = r[t][m];
            }
        }
    }
}

// ---------------------------------------------------------------------------
// MLP fwd+bwd, channel-split: 256 thr = 64 samples x 4 ch-groups of 16.
// ---------------------------------------------------------------------------
__global__ __launch_bounds__(256) void mlp4(
    const float* __restrict__ h, const float* __restrict__ A1,
    const float* __restrict__ A2, const float* __restrict__ a1t,
    const float* __restrict__ a2t, const float* __restrict__ a3t,
    const float* __restrict__ b1, const float* __restrict__ b2,
    const float* __restrict__ b3, const float* __restrict__ dg2,
    float* __restrict__ xout, float* __restrict__ dhout, int n)
{
    __shared__ float sact[64][65];
    const int tid  = threadIdx.x;
    const int lane = tid & 63;
    const int ch0  = __builtin_amdgcn_readfirstlane((tid >> 6) * 16);  // wave-uniform
    const int s    = blockIdx.x * 64 + lane;
    const bool valid = s < n;
    const int sld  = valid ? s : (n - 1);

    // stage h chunk: this thread's sample, its 16 channels
    {
        const float* hp = h + (size_t)sld * 64 + ch0;
        #pragma unroll
        for (int q = 0; q < 4; ++q) {
            float4 v = *(const float4*)(hp + 4 * q);
            sact[lane][ch0 + 4 * q + 0] = v.x;
            sact[lane][ch0 + 4 * q + 1] = v.y;
            sact[lane][ch0 + 4 * q + 2] = v.z;
            sact[lane][ch0 + 4 * q + 3] = v.w;
        }
    }
    __syncthreads();

    float acc[16], z1[16], z2[16];

    // ---- L1: z1 = h @ A1.T + b1
    #pragma unroll
    for (int k = 0; k < 16; ++k) acc[k] = b1[ch0 + k];
    #pragma unroll 4
    for (int j = 0; j < 64; ++j) {
        float aj = sact[lane][j];
        const float* r = a1t + j * 64 + ch0;
        #pragma unroll
        for (int k = 0; k < 16; ++k) acc[k] += aj * r[k];
    }
    __syncthreads();               // all reads of h-tile done
    #pragma unroll
    for (int k = 0; k < 16; ++k) {
        float z = acc[k]; z1[k] = z;
        float sg = 1.f / (1.f + __expf(-z));
        sact[lane][ch0 + k] = z * sg;
    }
    __syncthreads();

    // ---- L2: z2 = g1 @ A2.T + b2
    #pragma unroll
    for (int k = 0; k < 16; ++k) acc[k] = b2[ch0 + k];
    #pragma unroll 4
    for (int j = 0; j < 64; ++j) {
        float aj = sact[lane][j];
        const float* r = a2t + j * 64 + ch0;
        #pragma unroll
        for (int k = 0; k < 16; ++k) acc[k] += aj * r[k];
    }
    __syncthreads();
    #pragma unroll
    for (int k = 0; k < 16; ++k) {
        float z = acc[k]; z2[k] = z;
        float sg = 1.f / (1.f + __expf(-z));
        sact[lane][ch0 + k] = z * sg;
    }
    __syncthreads();

    // ---- L3: x = g2 @ A3.T + b3
    #pragma unroll
    for (int k = 0; k < 16; ++k) acc[k] = b3[ch0 + k];
    #pragma unroll 4
    for (int j = 0; j < 64; ++j) {
        float aj = sact[lane][j];
        const float* r = a3t + j * 64 + ch0;
        #pragma unroll
        for (int k = 0; k < 16; ++k) acc[k] += aj * r[k];
    }
    if (valid) {
        float4* xo = (float4*)(xout + (size_t)s * 64 + ch0);
        #pragma unroll
        for (int q = 0; q < 4; ++q)
            xo[q] = make_float4(acc[4 * q], acc[4 * q + 1], acc[4 * q + 2], acc[4 * q + 3]);
    }

    // ---- bwd: dz2 = dg2 * silu'(z2)
    __syncthreads();               // L3 reads of g2 done
    #pragma unroll
    for (int k = 0; k < 16; ++k) {
        float z = z2[k];
        float sg = 1.f / (1.f + __expf(-z));
        sact[lane][ch0 + k] = dg2[ch0 + k] * sg * (1.f + z * (1.f - sg));
    }
    __syncthreads();

    // ---- dg1[j] = sum_k dz2[k] * A2[k][j] ; dz1 = dg1 * silu'(z1)
    #pragma unroll
    for (int k = 0; k < 16; ++k) acc[k] = 0.f;
    #pragma unroll 4
    for (int kk = 0; kk < 64; ++kk) {
        float d = sact[lane][kk];
        const float* r = A2 + kk * 64 + ch0;
        #pragma unroll
        for (int k = 0; k < 16; ++k) acc[k] += d * r[k];
    }
    __syncthreads();
    #pragma unroll
    for (int k = 0; k < 16; ++k) {
        float z = z1[k];
        float sg = 1.f / (1.f + __expf(-z));
        sact[lane][ch0 + k] = acc[k] * sg * (1.f + z * (1.f - sg));
    }
    __syncthreads();

    // ---- dh[i] = sum_j dz1[j] * A1[j][i]
    #pragma unroll
    for (int k = 0; k < 16; ++k) acc[k] = 0.f;
    #pragma unroll 4
    for (int j = 0; j < 64; ++j) {
        float d = sact[lane][j];
        const float* r = A1 + j * 64 + ch0;
        #pragma unroll
        for (int k = 0; k < 16; ++k) acc[k] += d * r[k];
    }
    if (valid) {
        float4* dho = (float4*)(dhout + (size_t)s * 64 + ch0);
        #pragma unroll
        for (int q = 0; q < 4; ++q)
            dho[q] = make_float4(acc[4 * q], acc[4 * q + 1], acc[4 * q + 2], acc[4 * q + 3]);
    }
}

// ---------------------------------------------------------------------------
extern "C" void kernel_launch(void* const* d_in, const int* in_sizes, int n_in,
                              void* d_out, int out_size, void* d_ws, size_t ws_size,
                              hipStream_t stream)
{
    const float* tin = (const float*)d_in[0];
    const float* W0  = (const float*)d_in[1];
    const float* W1  = (const float*)d_in[2];
    const float* W2  = (const float*)d_in[3];
    const float* A1  = (const float*)d_in[4];
    const float* b1  = (const float*)d_in[5];
    const float* A2  = (const float*)d_in[6];
    const float* b2  = (const float*)d_in[7];
    const float* A3  = (const float*)d_in[8];
    const float* b3  = (const float*)d_in[9];
    float* out = (float*)d_out;
    char* ws   = (char*)d_ws;
    const int n = in_sizes[0] / IRR;

    unsigned short* wtf = (unsigned short*)(ws + B_WTF);
    unsigned short* wb  = (unsigned short*)(ws + B_WB);
    float* a1t  = (float*)(ws + B_A1T);
    float* a2t  = (float*)(ws + B_A2T);
    float* a3t  = (float*)(ws + B_A3T);
    float* dg2  = (float*)(ws + B_DG2);
    float* h    = (float*)(ws + B_H);
    float* dh   = h + (size_t)n * 64;
    float* xout = out;
    float* yout = out + (size_t)n * 64;

    const int total_prep = 64 * NP + 5376 * 64 + 3 * 4096 + 64;
    prep_kernel<<<(total_prep + 255) / 256, 256, 0, stream>>>(W0, W1, W2, A1, A2, A3,
                                                              wtf, wb, a1t, a2t, a3t, dg2);
    const int nb64 = (n + 63) / 64;
    fctp_fwd4<<<nb64, 256, 0, stream>>>(tin, wtf, h, n);
    mlp4<<<nb64, 256, 0, stream>>>(h, A1, A2, a1t, a2t, a3t,
                                   b1, b2, b3, dg2, xout, dh, n);
    fctp_bwd_l0<<<dim3(nb64, 4), 256, 0, stream>>>(tin, wb, dh, yout, n);
    fctp_bwd_l12<<<dim3((nb64 + 3) / 4, 3), 256, 0, stream>>>(tin, wb, dh, yout, n);
}